// Round 1
// baseline (718.585 us; speedup 1.0000x reference)
//
#include <hip/hip_runtime.h>

#define NNODES 250000
#define NGRAPH 512
#define RDIM   128
#define NRBF   32
#define ATDIM  32
#define EDIM   384

#define BN       64     // nodes per block
#define STRIDE_A 164    // 160 cols + pad (keeps 16B alignment: 164*4 % 16 == 0)
#define STRIDE_B 132    // 128 cols + pad

__device__ __forceinline__ float gelu_f(float x) {
    // jax.nn.gelu(approximate=True): 0.5*x*(1+tanh(sqrt(2/pi)*(x+0.044715 x^3)))
    float u  = 0.7978845608028654f * (x + 0.044715f * x * x * x);
    float e  = __expf(2.0f * u);               // overflow->inf -> tanh=1 (correct limit)
    float th = 1.0f - 2.0f / (e + 1.0f);
    return 0.5f * x * (1.0f + th);
}

__device__ __forceinline__ void fma4(float4& acc, float s, const float4& w) {
    acc.x = fmaf(s, w.x, acc.x);
    acc.y = fmaf(s, w.y, acc.y);
    acc.z = fmaf(s, w.z, acc.z);
    acc.w = fmaf(s, w.w, acc.w);
}

// One dense layer: out[64 x 128] = act(in[64 x K] @ W[K x 128] + bias)
// Thread tile: 8 nodes x 4 channels. cg = tid&31 (c0=cg*4), ng = tid>>5 (n0=ng*8).
template<int K, bool GELU, bool SCALE>
__device__ __forceinline__ void layer(const float* __restrict__ in_lds, int in_stride,
                                      const float* __restrict__ W,
                                      const float* __restrict__ bias,
                                      float* __restrict__ out_lds, int out_stride,
                                      int tid)
{
    const int cg = tid & 31;
    const int ng = tid >> 5;
    const int c0 = cg * 4;
    const int n0 = ng * 8;

    float4 binit;
    if (bias) binit = *(const float4*)(bias + c0);
    else      binit = make_float4(0.f, 0.f, 0.f, 0.f);

    float4 acc[8];
    #pragma unroll
    for (int n = 0; n < 8; ++n) acc[n] = binit;

    #pragma unroll 4
    for (int k = 0; k < K; k += 4) {
        float4 a[8];
        #pragma unroll
        for (int n = 0; n < 8; ++n)
            a[n] = *(const float4*)(in_lds + (n0 + n) * in_stride + k);
        float4 w0 = *(const float4*)(W + (k + 0) * RDIM + c0);
        float4 w1 = *(const float4*)(W + (k + 1) * RDIM + c0);
        float4 w2 = *(const float4*)(W + (k + 2) * RDIM + c0);
        float4 w3 = *(const float4*)(W + (k + 3) * RDIM + c0);
        #pragma unroll
        for (int n = 0; n < 8; ++n) {
            fma4(acc[n], a[n].x, w0);
            fma4(acc[n], a[n].y, w1);
            fma4(acc[n], a[n].z, w2);
            fma4(acc[n], a[n].w, w3);
        }
    }

    #pragma unroll
    for (int n = 0; n < 8; ++n) {
        float4 v = acc[n];
        if (GELU) {
            v.x = gelu_f(v.x); v.y = gelu_f(v.y);
            v.z = gelu_f(v.z); v.w = gelu_f(v.w);
        }
        if (SCALE) {
            const float s = 0.08838834764831845f;  // 1/sqrt(128)
            v.x *= s; v.y *= s; v.z *= s; v.w *= s;
        }
        *(float4*)(out_lds + (n0 + n) * out_stride + c0) = v;
    }
}

__global__ __launch_bounds__(256, 2)
void encoder_kernel(const float* __restrict__ pos, const int* __restrict__ z,
                    const int* __restrict__ batch,
                    const float* __restrict__ node_table,
                    const float* __restrict__ w_r1, const float* __restrict__ b_r1,
                    const float* __restrict__ w_r2, const float* __restrict__ b_r2,
                    const float* __restrict__ w_m1, const float* __restrict__ b_m1,
                    const float* __restrict__ w_m2, const float* __restrict__ b_m2,
                    const float* __restrict__ w_m3, const float* __restrict__ b_m3,
                    const float* __restrict__ w_tp,
                    float* __restrict__ sums, float* __restrict__ cnt)
{
    __shared__ float A[BN * STRIDE_A];
    __shared__ float B[BN * STRIDE_B];
    __shared__ float sh_s[BN][3];
    __shared__ float dist_s[BN];
    __shared__ int   z_s[BN];
    __shared__ int   batch_s[BN];

    const int tid   = threadIdx.x;
    const int node0 = blockIdx.x * BN;

    // ---- P0a: per-node scalar inputs ----
    if (tid < BN) {
        int gn = node0 + tid;
        float px = 0.f, py = 0.f, pz = 0.f;
        int zz = 0, bb = -1;
        if (gn < NNODES) {
            px = pos[gn * 3 + 0];
            py = pos[gn * 3 + 1];
            pz = pos[gn * 3 + 2];
            zz = z[gn];
            bb = batch[gn];
        }
        dist_s[tid] = sqrtf(px * px + py * py + pz * pz);
        const float s3 = 1.7320508075688772f;   // sqrt(3), 'component' norm l=1
        sh_s[tid][0] = s3 * py;                 // (y, z, x) order
        sh_s[tid][1] = s3 * pz;
        sh_s[tid][2] = s3 * px;
        z_s[tid] = zz;
        batch_s[tid] = bb;
    }
    __syncthreads();

    // ---- P0b: gaussian RBF -> A[:, 0..31] ----
    {
        const float step  = 1.0f / 31.0f;
        const float coeff = -0.5f / (step * step);
        #pragma unroll
        for (int t = 0; t < (BN * NRBF) / 256; ++t) {
            int idx = tid + t * 256;
            int n = idx >> 5, k = idx & 31;
            float d = dist_s[n] - (float)k * step;
            A[n * STRIDE_A + k] = expf(coeff * d * d);
        }
    }
    __syncthreads();

    // ---- P1: r1 = gelu(rbf @ w_r1 + b_r1) -> B ----
    layer<NRBF, true, false>(A, STRIDE_A, w_r1, b_r1, B, STRIDE_B, tid);
    __syncthreads();

    // ---- P2: h0 = r1 @ w_r2 + b_r2 -> A[:,0:128]; nemb -> A[:,128:160] ----
    layer<RDIM, false, false>(B, STRIDE_B, w_r2, b_r2, A, STRIDE_A, tid);
    #pragma unroll
    for (int t = 0; t < (BN * ATDIM) / 256; ++t) {
        int idx = tid + t * 256;
        int n = idx >> 5, j = idx & 31;
        A[n * STRIDE_A + RDIM + j] = node_table[z_s[n] * ATDIM + j];
    }
    __syncthreads();

    // ---- P3: h1 = gelu(h @ w_m1 + b_m1) -> B ----
    layer<RDIM + ATDIM, true, false>(A, STRIDE_A, w_m1, b_m1, B, STRIDE_B, tid);
    __syncthreads();

    // ---- P4: h2 = gelu(h1 @ w_m2 + b_m2) -> A ----
    layer<RDIM, true, false>(B, STRIDE_B, w_m2, b_m2, A, STRIDE_A, tid);
    __syncthreads();

    // ---- P5: msg = h2 @ w_m3 + b_m3 -> B ----
    layer<RDIM, false, false>(A, STRIDE_A, w_m3, b_m3, B, STRIDE_B, tid);
    __syncthreads();

    // ---- P6: t = (msg @ w_tp) / sqrt(128) -> A ----
    layer<RDIM, false, true>(B, STRIDE_B, w_tp, nullptr, A, STRIDE_A, tid);
    __syncthreads();

    // ---- P7: segmented pooling: sums[g][m*3+c] += t[n][m] * sh[n][c] ----
    // batch is sorted -> a block spans few graphs; one atomic per (segment, col).
    for (int j = tid; j < EDIM; j += 256) {
        int m = j / 3, c = j - m * 3;
        float s = 0.0f;
        int gcur = batch_s[0];
        for (int n = 0; n < BN; ++n) {
            int g = batch_s[n];
            if (g != gcur) {
                if (gcur >= 0) atomicAdd(sums + gcur * EDIM + j, s);
                s = 0.0f;
                gcur = g;
            }
            s = fmaf(A[n * STRIDE_A + m], sh_s[n][c], s);
        }
        if (gcur >= 0) atomicAdd(sums + gcur * EDIM + j, s);
    }

    if (tid == 0) {
        float c = 0.0f;
        int gcur = batch_s[0];
        for (int n = 0; n < BN; ++n) {
            int g = batch_s[n];
            if (g != gcur) {
                if (gcur >= 0) atomicAdd(cnt + gcur, c);
                c = 0.0f;
                gcur = g;
            }
            c += 1.0f;
        }
        if (gcur >= 0) atomicAdd(cnt + gcur, c);
    }
}

__global__ void finalize_kernel(const float* __restrict__ sums,
                                const float* __restrict__ cnt,
                                float* __restrict__ out)
{
    int i = blockIdx.x * blockDim.x + threadIdx.x;
    if (i < NGRAPH * EDIM) {
        int g = i / EDIM;
        float m = fmaxf(cnt[g], 1.0f);
        out[i] = sums[i] * (1.0f + 1.0f / m);   // mean + sums
    }
}

extern "C" void kernel_launch(void* const* d_in, const int* in_sizes, int n_in,
                              void* d_out, int out_size, void* d_ws, size_t ws_size,
                              hipStream_t stream) {
    const float* pos        = (const float*)d_in[0];
    const int*   z          = (const int*)d_in[1];
    const int*   batch      = (const int*)d_in[2];
    // d_in[3] = num_graphs scalar (fixed at 512, compile-time)
    const float* node_table = (const float*)d_in[4];
    const float* w_r1       = (const float*)d_in[5];
    const float* b_r1       = (const float*)d_in[6];
    const float* w_r2       = (const float*)d_in[7];
    const float* b_r2       = (const float*)d_in[8];
    const float* w_m1       = (const float*)d_in[9];
    const float* b_m1       = (const float*)d_in[10];
    const float* w_m2       = (const float*)d_in[11];
    const float* b_m2       = (const float*)d_in[12];
    const float* w_m3       = (const float*)d_in[13];
    const float* b_m3       = (const float*)d_in[14];
    const float* w_tp       = (const float*)d_in[15];

    float* sums = (float*)d_ws;
    float* cnt  = sums + NGRAPH * EDIM;
    float* out  = (float*)d_out;

    // ws is re-poisoned to 0xAA before every launch -> zero what we accumulate into
    hipMemsetAsync(d_ws, 0, (NGRAPH * EDIM + NGRAPH) * sizeof(float), stream);

    int nblocks = (NNODES + BN - 1) / BN;   // 3907
    encoder_kernel<<<nblocks, 256, 0, stream>>>(
        pos, z, batch, node_table,
        w_r1, b_r1, w_r2, b_r2,
        w_m1, b_m1, w_m2, b_m2, w_m3, b_m3, w_tp,
        sums, cnt);

    finalize_kernel<<<(NGRAPH * EDIM + 255) / 256, 256, 0, stream>>>(sums, cnt, out);
}

// Round 3
// 301.535 us; speedup vs baseline: 2.3831x; 2.3831x over previous
//
#include <hip/hip_runtime.h>

#define NNODES 250000
#define NGRAPH 512
#define RDIM   128
#define NRBF   32
#define ATDIM  32
#define EDIM   384
#define BN     64

typedef _Float16 f16x8 __attribute__((ext_vector_type(8)));
typedef float    f32x16 __attribute__((ext_vector_type(16)));

// Prepacked-weight fragment bases (in f16 elements = frag_index * 512)
#define OFF_L1 0          // frags 0-7    (K=32)
#define OFF_L2 4096       // frags 8-39   (K=128)
#define OFF_L3 20480      // frags 40-79  (K=160)
#define OFF_L4 40960      // frags 80-111
#define OFF_L5 57344      // frags 112-143
#define OFF_L6 73728      // frags 144-175
#define NWELEM 90112

__device__ __forceinline__ float gelu_f(float x) {
    float u  = 0.7978845608028654f * (x + 0.044715f * x * x * x);
    float e  = __expf(2.0f * u);
    float th = 1.0f - 2.0f / (e + 1.0f);
    return 0.5f * x * (1.0f + th);
}

// ---- weight prepack: split f32 -> (hi,lo) f16, B-fragment order ----
// frag f: kb = (f-fb)>>2, nb = (f-fb)&3; lane holds col = nb*32+(lane&31),
// k = kb*16 + 8*(lane>>5) + e, e=0..7 -> element index f*512 + lane*8 + e.
__global__ void prepack_kernel(const float* __restrict__ w_r1,
                               const float* __restrict__ w_r2,
                               const float* __restrict__ w_m1,
                               const float* __restrict__ w_m2,
                               const float* __restrict__ w_m3,
                               const float* __restrict__ w_tp,
                               _Float16* __restrict__ Wh,
                               _Float16* __restrict__ Wl)
{
    int g = blockIdx.x * 256 + threadIdx.x;      // 0 .. 90111
    if (g >= NWELEM) return;
    int frag = g >> 9;
    int lane = (g >> 3) & 63;
    int e    = g & 7;
    const float* W; int fb; float scale = 1.0f;
    if      (frag <   8) { W = w_r1; fb = 0;   }
    else if (frag <  40) { W = w_r2; fb = 8;   }
    else if (frag <  80) { W = w_m1; fb = 40;  }
    else if (frag < 112) { W = w_m2; fb = 80;  }
    else if (frag < 144) { W = w_m3; fb = 112; }
    else                 { W = w_tp; fb = 144; scale = 0.08838834764831845f; } // 1/sqrt(128)
    int fl = frag - fb;
    int kb = fl >> 2, nb = fl & 3;
    int k   = kb * 16 + 8 * (lane >> 5) + e;
    int col = nb * 32 + (lane & 31);
    float w = W[k * RDIM + col] * scale;
    _Float16 h = (_Float16)w;
    _Float16 l = (_Float16)(w - (float)h);
    Wh[g] = h;
    Wl[g] = l;
}

// ---- one dense layer on MFMA (hi/lo split, 3 terms) ----
// Wave (wr,wc) computes C rows [wr*32,+32), cols [wc*64,+64) as 2 32x32 frags.
// Input activations: swizzled f16 LDS [64][128]: idx = row*128 + (col ^ ((row&15)<<3))
template<int KS, bool NEMB, bool GELU, bool TOUT>
__device__ __forceinline__ void layer_mfma(
    const _Float16* __restrict__ Wh, const _Float16* __restrict__ Wl,
    const float* __restrict__ bias,
    _Float16* acth, _Float16* actl,
    const _Float16* nh, const _Float16* nl,
    float* tbuf,
    int lane, int wr, int wc)
{
    const int l31 = lane & 31, hh = lane >> 5;
    const int arow  = wr * 32 + l31;
    const int abase = arow * 128;
    const int aswz  = (arow & 15) << 3;

    float b0 = 0.0f, b1 = 0.0f;
    if (bias) { b0 = bias[wc * 64 + l31]; b1 = bias[wc * 64 + 32 + l31]; }
    f32x16 acc0, acc1;
    #pragma unroll
    for (int e = 0; e < 16; ++e) { acc0[e] = b0; acc1[e] = b1; }

    const f16x8* __restrict__ WhF = (const f16x8*)Wh;
    const f16x8* __restrict__ WlF = (const f16x8*)Wl;

    #pragma unroll
    for (int ks = 0; ks < KS; ++ks) {
        int cx = abase + ((ks * 16 + 8 * hh) ^ aswz);
        f16x8 ah = *(const f16x8*)(acth + cx);
        f16x8 al = *(const f16x8*)(actl + cx);
        int f0 = (ks * 4 + wc * 2) * 64 + lane;
        f16x8 bh0 = WhF[f0],      bl0 = WlF[f0];
        f16x8 bh1 = WhF[f0 + 64], bl1 = WlF[f0 + 64];
        acc0 = __builtin_amdgcn_mfma_f32_32x32x16_f16(ah, bh0, acc0, 0, 0, 0);
        acc1 = __builtin_amdgcn_mfma_f32_32x32x16_f16(ah, bh1, acc1, 0, 0, 0);
        acc0 = __builtin_amdgcn_mfma_f32_32x32x16_f16(al, bh0, acc0, 0, 0, 0);
        acc1 = __builtin_amdgcn_mfma_f32_32x32x16_f16(al, bh1, acc1, 0, 0, 0);
        acc0 = __builtin_amdgcn_mfma_f32_32x32x16_f16(ah, bl0, acc0, 0, 0, 0);
        acc1 = __builtin_amdgcn_mfma_f32_32x32x16_f16(ah, bl1, acc1, 0, 0, 0);
    }
    if (NEMB) {   // extra K 128..159 from nemb arrays (stride 64, swizzle (row&7)<<3)
        const int nbase = arow * 64, nswz = (arow & 7) << 3;
        #pragma unroll
        for (int s = 0; s < 2; ++s) {
            int cx = nbase + ((s * 16 + 8 * hh) ^ nswz);
            f16x8 ah = *(const f16x8*)(nh + cx);
            f16x8 al = *(const f16x8*)(nl + cx);
            int f0 = ((KS + s) * 4 + wc * 2) * 64 + lane;
            f16x8 bh0 = WhF[f0],      bl0 = WlF[f0];
            f16x8 bh1 = WhF[f0 + 64], bl1 = WlF[f0 + 64];
            acc0 = __builtin_amdgcn_mfma_f32_32x32x16_f16(ah, bh0, acc0, 0, 0, 0);
            acc1 = __builtin_amdgcn_mfma_f32_32x32x16_f16(ah, bh1, acc1, 0, 0, 0);
            acc0 = __builtin_amdgcn_mfma_f32_32x32x16_f16(al, bh0, acc0, 0, 0, 0);
            acc1 = __builtin_amdgcn_mfma_f32_32x32x16_f16(al, bh1, acc1, 0, 0, 0);
            acc0 = __builtin_amdgcn_mfma_f32_32x32x16_f16(ah, bl0, acc0, 0, 0, 0);
            acc1 = __builtin_amdgcn_mfma_f32_32x32x16_f16(ah, bl1, acc1, 0, 0, 0);
        }
    }
    __syncthreads();   // all reads of the activation buffer complete

    // epilogue: C layout col=lane&31(+nb*32+wc*64), row=wr*32+4*(lane>>5)+(e&3)+8*(e>>2)
    const int c0 = wc * 64 + l31, c1 = c0 + 32;
    #pragma unroll
    for (int e = 0; e < 16; ++e) {
        int row = wr * 32 + 4 * hh + ((e & 3) + 8 * (e >> 2));
        float v0 = acc0[e], v1 = acc1[e];
        if (GELU) { v0 = gelu_f(v0); v1 = gelu_f(v1); }
        if (TOUT) {
            tbuf[row * 128 + c0] = v0;
            tbuf[row * 128 + c1] = v1;
        } else {
            int swz = (row & 15) << 3;
            int i0 = row * 128 + (c0 ^ swz);
            int i1 = row * 128 + (c1 ^ swz);
            _Float16 h0 = (_Float16)v0;
            acth[i0] = h0; actl[i0] = (_Float16)(v0 - (float)h0);
            _Float16 h1 = (_Float16)v1;
            acth[i1] = h1; actl[i1] = (_Float16)(v1 - (float)h1);
        }
    }
    __syncthreads();   // outputs visible for next layer
}

__global__ __launch_bounds__(256, 3)
void encoder_kernel(const float* __restrict__ pos, const int* __restrict__ z,
                    const int* __restrict__ batch,
                    const float* __restrict__ node_table,
                    const float* __restrict__ b_r1, const float* __restrict__ b_r2,
                    const float* __restrict__ b_m1, const float* __restrict__ b_m2,
                    const float* __restrict__ b_m3,
                    const _Float16* __restrict__ Wh, const _Float16* __restrict__ Wl,
                    float* __restrict__ sums, float* __restrict__ cnt)
{
    __shared__ union {
        struct { _Float16 hi[BN * 128]; _Float16 lo[BN * 128]; } h;  // 32 KB
        float t[BN * 128];                                           // 32 KB (aliases)
    } actU;
    __shared__ _Float16 nemb_hi[BN * 64];   // stride 64, cols 0-31 used
    __shared__ _Float16 nemb_lo[BN * 64];
    __shared__ float sh_s[BN][3];
    __shared__ float dist_s[BN];
    __shared__ int   z_s[BN];
    __shared__ int   batch_s[BN];

    const int tid  = threadIdx.x;
    const int lane = tid & 63;
    const int wv   = tid >> 6;
    const int wr   = wv >> 1, wc = wv & 1;
    const int node0 = blockIdx.x * BN;

    // ---- P0a: per-node scalars ----
    if (tid < BN) {
        int gn = node0 + tid;
        float px = 0.f, py = 0.f, pz = 0.f;
        int zz = 0, bb = -1;
        if (gn < NNODES) {
            px = pos[gn * 3 + 0]; py = pos[gn * 3 + 1]; pz = pos[gn * 3 + 2];
            zz = z[gn]; bb = batch[gn];
        }
        dist_s[tid] = sqrtf(px * px + py * py + pz * pz);
        const float s3 = 1.7320508075688772f;
        sh_s[tid][0] = s3 * py; sh_s[tid][1] = s3 * pz; sh_s[tid][2] = s3 * px;
        z_s[tid] = zz; batch_s[tid] = bb;
    }
    __syncthreads();

    // ---- P0b: RBF -> act[:,0:32] (hi/lo, swizzled); nemb -> nemb arrays ----
    {
        const float step  = 1.0f / 31.0f;
        const float coeff = -0.5f / (step * step);
        #pragma unroll
        for (int t = 0; t < (BN * NRBF) / 256; ++t) {
            int idx = tid + t * 256;
            int n = idx >> 5, k = idx & 31;
            float d = dist_s[n] - (float)k * step;
            float x = expf(coeff * d * d);
            _Float16 h = (_Float16)x;
            int i = n * 128 + (k ^ ((n & 15) << 3));
            actU.h.hi[i] = h;
            actU.h.lo[i] = (_Float16)(x - (float)h);
        }
        #pragma unroll
        for (int t = 0; t < (BN * ATDIM) / 256; ++t) {
            int idx = tid + t * 256;
            int n = idx >> 5, j = idx & 31;
            float x = node_table[z_s[n] * ATDIM + j];
            _Float16 h = (_Float16)x;
            int i = n * 64 + (j ^ ((n & 7) << 3));
            nemb_hi[i] = h;
            nemb_lo[i] = (_Float16)(x - (float)h);
        }
    }
    __syncthreads();

    _Float16* ah = actU.h.hi;
    _Float16* al = actU.h.lo;

    // L1: gelu(rbf @ w_r1 + b_r1)          K=32
    layer_mfma<2, false, true,  false>(Wh + OFF_L1, Wl + OFF_L1, b_r1, ah, al, nemb_hi, nemb_lo, nullptr, lane, wr, wc);
    // L2: r_emb = (.. @ w_r2 + b_r2)       K=128
    layer_mfma<8, false, false, false>(Wh + OFF_L2, Wl + OFF_L2, b_r2, ah, al, nemb_hi, nemb_lo, nullptr, lane, wr, wc);
    // L3: gelu([r_emb,nemb] @ w_m1 + b_m1) K=160
    layer_mfma<8, true,  true,  false>(Wh + OFF_L3, Wl + OFF_L3, b_m1, ah, al, nemb_hi, nemb_lo, nullptr, lane, wr, wc);
    // L4: gelu(.. @ w_m2 + b_m2)           K=128
    layer_mfma<8, false, true,  false>(Wh + OFF_L4, Wl + OFF_L4, b_m2, ah, al, nemb_hi, nemb_lo, nullptr, lane, wr, wc);
    // L5: msg = .. @ w_m3 + b_m3           K=128
    layer_mfma<8, false, false, false>(Wh + OFF_L5, Wl + OFF_L5, b_m3, ah, al, nemb_hi, nemb_lo, nullptr, lane, wr, wc);
    // L6: t = msg @ (w_tp/sqrt(128))       K=128, f32 out -> tbuf
    layer_mfma<8, false, false, true >(Wh + OFF_L6, Wl + OFF_L6, nullptr, ah, al, nemb_hi, nemb_lo, actU.t, lane, wr, wc);

    // ---- P7: segmented pooling: sums[g][m*3+c] += t[n][m] * sh[n][c] ----
    for (int j = tid; j < EDIM; j += 256) {
        int m = j / 3, c = j - m * 3;
        float s = 0.0f;
        int gcur = batch_s[0];
        for (int n = 0; n < BN; ++n) {
            int g = batch_s[n];
            if (g != gcur) {
                if (gcur >= 0) atomicAdd(sums + gcur * EDIM + j, s);
                s = 0.0f;
                gcur = g;
            }
            s = fmaf(actU.t[n * 128 + m], sh_s[n][c], s);
        }
        if (gcur >= 0) atomicAdd(sums + gcur * EDIM + j, s);
    }

    if (tid == 0) {
        float c = 0.0f;
        int gcur = batch_s[0];
        for (int n = 0; n < BN; ++n) {
            int g = batch_s[n];
            if (g != gcur) {
                if (gcur >= 0) atomicAdd(cnt + gcur, c);
                c = 0.0f;
                gcur = g;
            }
            c += 1.0f;
        }
        if (gcur >= 0) atomicAdd(cnt + gcur, c);
    }
}

__global__ void finalize_kernel(const float* __restrict__ sums,
                                const float* __restrict__ cnt,
                                float* __restrict__ out)
{
    int i = blockIdx.x * blockDim.x + threadIdx.x;
    if (i < NGRAPH * EDIM) {
        int g = i / EDIM;
        float m = fmaxf(cnt[g], 1.0f);
        out[i] = sums[i] * (1.0f + 1.0f / m);
    }
}

extern "C" void kernel_launch(void* const* d_in, const int* in_sizes, int n_in,
                              void* d_out, int out_size, void* d_ws, size_t ws_size,
                              hipStream_t stream) {
    const float* pos        = (const float*)d_in[0];
    const int*   zz         = (const int*)d_in[1];
    const int*   batch      = (const int*)d_in[2];
    const float* node_table = (const float*)d_in[4];
    const float* w_r1       = (const float*)d_in[5];
    const float* b_r1       = (const float*)d_in[6];
    const float* w_r2       = (const float*)d_in[7];
    const float* b_r2       = (const float*)d_in[8];
    const float* w_m1       = (const float*)d_in[9];
    const float* b_m1       = (const float*)d_in[10];
    const float* w_m2       = (const float*)d_in[11];
    const float* b_m2       = (const float*)d_in[12];
    const float* w_m3       = (const float*)d_in[13];
    const float* b_m3       = (const float*)d_in[14];
    const float* w_tp       = (const float*)d_in[15];

    // workspace: sums | cnt | Wh | Wl   (~1.13 MB)
    float*    sums = (float*)d_ws;
    float*    cnt  = sums + NGRAPH * EDIM;
    _Float16* Wh   = (_Float16*)(cnt + NGRAPH);
    _Float16* Wl   = Wh + NWELEM;
    float*    out  = (float*)d_out;

    hipMemsetAsync(d_ws, 0, (NGRAPH * EDIM + NGRAPH) * sizeof(float), stream);

    prepack_kernel<<<(NWELEM + 255) / 256, 256, 0, stream>>>(
        w_r1, w_r2, w_m1, w_m2, w_m3, w_tp, Wh, Wl);

    int nblocks = (NNODES + BN - 1) / BN;   // 3907
    encoder_kernel<<<nblocks, 256, 0, stream>>>(
        pos, zz, batch, node_table,
        b_r1, b_r2, b_m1, b_m2, b_m3,
        Wh, Wl, sums, cnt);

    finalize_kernel<<<(NGRAPH * EDIM + 255) / 256, 256, 0, stream>>>(sums, cnt, out);
}